// Round 2
// baseline (671.086 us; speedup 1.0000x reference)
//
#include <hip/hip_runtime.h>
#include <hip/hip_bf16.h>

typedef short s16x8 __attribute__((ext_vector_type(8)));
typedef float f32x4 __attribute__((ext_vector_type(4)));

#define MFMA_BF16(a,b,c) __builtin_amdgcn_mfma_f32_16x16x32_bf16((a),(b),(c),0,0,0)

static __device__ __forceinline__ unsigned short f2bf(float f){
  unsigned u = __builtin_bit_cast(unsigned, f);
  u += 0x7fffu + ((u >> 16) & 1u);          // RNE
  return (unsigned short)(u >> 16);
}
static __device__ __forceinline__ float bf2f(unsigned short h){
  unsigned u = ((unsigned)h) << 16;
  return __builtin_bit_cast(float, u);
}
// XOR swizzle on 16B chunks; mask (row ^ row>>3)&7 gives 4 distinct slots for
// rows {r,4+r,8+r,12+r} (phase-D write groups) and 2-way (free) for 16
// consecutive rows (phase-E reads). lw = row width in shorts.
static __device__ __forceinline__ int swzi(int row, int col, int lw){
  const int chunk = (col >> 3) ^ ((row ^ (row >> 3)) & 7);
  return row*lw + (chunk << 3) + (col & 7);
}

// ---------------- kernel 0: W transpose + hi/lo split ------------------------
__global__ __launch_bounds__(128) void k0_wt(const float* __restrict__ W,
                                             unsigned short* __restrict__ wtH,
                                             unsigned short* __restrict__ wtL){
  const int n = blockIdx.x;       // 0..255 output col
  const int c = threadIdx.x;      // 0..127 input ch
  const float v = W[(size_t)c*256 + n];
  const unsigned short h = f2bf(v);
  wtH[n*128 + c] = h;
  wtL[n*128 + c] = f2bf(v - bf2f(h));
}

// ---------------- kernel 1: qkv = x @ W (split-bf16) -------------------------
// outputs: qh/ql/kh/kl bf16 planes [pos][64] (MFMA fragment order),
//          v bf16 transposed -> vT[head][ch][pos]
__global__ __launch_bounds__(512,4) void k1_qkv(const float* __restrict__ x,
    const unsigned short* __restrict__ wtH, const unsigned short* __restrict__ wtL,
    unsigned short* __restrict__ qh, unsigned short* __restrict__ ql,
    unsigned short* __restrict__ kh, unsigned short* __restrict__ kl,
    unsigned short* __restrict__ vT){
  __shared__ unsigned short xh[16384], xl[16384];   // 64 KB
  const int t = threadIdx.x;
  const int lane = t & 63, wid = t >> 6;
  const int li = lane & 15, g = lane >> 4;
  const int m0 = blockIdx.x * 128;
  const int wm = wid >> 2, wn = wid & 3;

  // stage x tile (128 rows x 128 ch), split hi/lo, swizzled
  {
    const int row = t >> 2, cb = (t & 3) * 32;
    const float* src = x + (size_t)(m0 + row)*128 + cb;
    #pragma unroll
    for (int gg = 0; gg < 4; ++gg){
      const float4 v0 = ((const float4*)src)[2*gg];
      const float4 v1 = ((const float4*)src)[2*gg + 1];
      const float vv[8] = {v0.x,v0.y,v0.z,v0.w,v1.x,v1.y,v1.z,v1.w};
      s16x8 h, l;
      #pragma unroll
      for (int j = 0; j < 8; ++j){
        const unsigned short hb = f2bf(vv[j]);
        h[j] = (short)hb;
        l[j] = (short)f2bf(vv[j] - bf2f(hb));
      }
      const int idx = swzi(row, cb + 8*gg, 128);
      *(s16x8*)&xh[idx] = h;
      *(s16x8*)&xl[idx] = l;
    }
  }
  __syncthreads();

  for (int nh = 0; nh < 2; ++nh){
    f32x4 acc[4][2] = {};
    #pragma unroll
    for (int ks = 0; ks < 4; ++ks){
      const int col = ks*32 + g*8;
      s16x8 ah[4], al[4];
      #pragma unroll
      for (int mi = 0; mi < 4; ++mi){
        const int idx = swzi(wm*64 + mi*16 + li, col, 128);
        ah[mi] = *(const s16x8*)&xh[idx];
        al[mi] = *(const s16x8*)&xl[idx];
      }
      #pragma unroll
      for (int ni = 0; ni < 2; ++ni){
        const size_t boff = (size_t)(nh*128 + wn*32 + ni*16 + li)*128 + col;
        const s16x8 bh = *(const s16x8*)(wtH + boff);
        const s16x8 bl = *(const s16x8*)(wtL + boff);
        #pragma unroll
        for (int mi = 0; mi < 4; ++mi){
          acc[mi][ni] = MFMA_BF16(ah[mi], bh, acc[mi][ni]);
          acc[mi][ni] = MFMA_BF16(ah[mi], bl, acc[mi][ni]);
          acc[mi][ni] = MFMA_BF16(al[mi], bh, acc[mi][ni]);
        }
      }
    }

    if (nh == 0){
      // cols 0..63 = q, 64..127 = k; wn uniform per wave
      #pragma unroll
      for (int mi = 0; mi < 4; ++mi)
        #pragma unroll
        for (int ni = 0; ni < 2; ++ni)
          #pragma unroll
          for (int r = 0; r < 4; ++r){
            const int grow = m0 + wm*64 + mi*16 + g*4 + r;
            const int coln = wn*32 + ni*16 + li;
            const float v = acc[mi][ni][r];
            const unsigned short h = f2bf(v);
            const unsigned short lo = f2bf(v - bf2f(h));
            const size_t off = (size_t)grow*64 + (coln & 63);
            if (wn < 2){ qh[off] = h; ql[off] = lo; }
            else       { kh[off] = h; kl[off] = lo; }
          }
    } else {
      #pragma unroll
      for (int mi = 0; mi < 4; ++mi)
        #pragma unroll
        for (int ni = 0; ni < 2; ++ni)
          #pragma unroll
          for (int r = 0; r < 4; ++r){
            const int grow = m0 + wm*64 + mi*16 + g*4 + r;
            const int ch = wn*32 + ni*16 + li;
            const int head = grow >> 9, pos = grow & 511;
            vT[((size_t)head << 16) + ch*512 + pos] = f2bf(acc[mi][ni][r]);
          }
    }
  }
}

// ---------------- kernel 2: scores -> softmax -> w out; y = x + w.v ---------
__global__ __launch_bounds__(512,4) void k2_attn(
    const unsigned short* __restrict__ qh, const unsigned short* __restrict__ ql,
    const unsigned short* __restrict__ kh, const unsigned short* __restrict__ kl,
    const unsigned short* __restrict__ vT, const float* __restrict__ x,
    float* __restrict__ y, float* __restrict__ wout){
  __shared__ unsigned short wlds[32768];          // 64 KB (swizzled bf16 w)
  __shared__ float redm[512], reds[512];          // cross-wave reductions

  const int t = threadIdx.x;
  const int lane = t & 63, wid = t >> 6;
  const int li = lane & 15, g = lane >> 4;
  const int bi = blockIdx.x;
  // XCD-grouped mapping: all 8 q-tiles of a head land on the same XCD
  const int head = (bi & 7) + 8*(bi >> 6);
  const int qt = (bi >> 3) & 7;
  const size_t hbase = (size_t)head * 512;
  const int q0 = qt * 64;
  const int kbase = wid * 64;                     // wave's k-slice

  // Phase B: scores(64 x 512), A/B fragments direct from global (L2-hot)
  f32x4 acc[4][4] = {};
  #pragma unroll
  for (int ks = 0; ks < 2; ++ks){
    const int col = ks*32 + g*8;
    s16x8 ah[4], al[4];
    #pragma unroll
    for (int mi = 0; mi < 4; ++mi){
      const size_t aoff = (hbase + q0 + mi*16 + li)*64 + col;
      ah[mi] = *(const s16x8*)(qh + aoff);
      al[mi] = *(const s16x8*)(ql + aoff);
    }
    #pragma unroll
    for (int ni = 0; ni < 4; ++ni){
      const size_t boff = (hbase + kbase + ni*16 + li)*64 + col;
      const s16x8 bh = *(const s16x8*)(kh + boff);
      const s16x8 bl = *(const s16x8*)(kl + boff);
      #pragma unroll
      for (int mi = 0; mi < 4; ++mi){
        acc[mi][ni] = MFMA_BF16(ah[mi], bh, acc[mi][ni]);
        acc[mi][ni] = MFMA_BF16(ah[mi], bl, acc[mi][ni]);
        acc[mi][ni] = MFMA_BF16(al[mi], bh, acc[mi][ni]);
      }
    }
  }

  // Phase C: exact softmax per row (in-wave shfl + cross-wave LDS)
  #pragma unroll
  for (int mi = 0; mi < 4; ++mi)
    #pragma unroll
    for (int r = 0; r < 4; ++r){
      float m = fmaxf(fmaxf(acc[mi][0][r], acc[mi][1][r]),
                      fmaxf(acc[mi][2][r], acc[mi][3][r]));
      #pragma unroll
      for (int d = 1; d < 16; d <<= 1) m = fmaxf(m, __shfl_xor(m, d));
      if (li == 0) redm[(mi*16 + g*4 + r)*8 + wid] = m;
    }
  __syncthreads();
  float inv[4][4];
  #pragma unroll
  for (int mi = 0; mi < 4; ++mi)
    #pragma unroll
    for (int r = 0; r < 4; ++r){
      const int row = mi*16 + g*4 + r;
      float m = redm[row*8];
      #pragma unroll
      for (int kk = 1; kk < 8; ++kk) m = fmaxf(m, redm[row*8 + kk]);
      float s = 0.f;
      #pragma unroll
      for (int ni = 0; ni < 4; ++ni){
        const float e = __expf(acc[mi][ni][r] - m);
        acc[mi][ni][r] = e;
        s += e;
      }
      #pragma unroll
      for (int d = 1; d < 16; d <<= 1) s += __shfl_xor(s, d);
      if (li == 0) reds[row*8 + wid] = s;
    }
  __syncthreads();
  #pragma unroll
  for (int mi = 0; mi < 4; ++mi)
    #pragma unroll
    for (int r = 0; r < 4; ++r){
      const int row = mi*16 + g*4 + r;
      float s = reds[row*8];
      #pragma unroll
      for (int kk = 1; kk < 8; ++kk) s += reds[row*8 + kk];
      inv[mi][r] = 1.0f / s;
    }

  // Phase D: write w (fp32, non-temporal) + stash bf16 copy in LDS for PV
  #pragma unroll
  for (int mi = 0; mi < 4; ++mi)
    #pragma unroll
    for (int ni = 0; ni < 4; ++ni)
      #pragma unroll
      for (int r = 0; r < 4; ++r){
        const int row = mi*16 + g*4 + r;
        const int col = kbase + ni*16 + li;
        const float wv = acc[mi][ni][r] * inv[mi][r];
        __builtin_nontemporal_store(wv, &wout[(hbase + q0 + row)*512 + col]);
        wlds[swzi(row, col, 512)] = f2bf(wv);
      }
  __syncthreads();

  // Phase E: y-tile = w . v ; wave owns 16 output channels
  const int c0 = wid * 16;
  f32x4 yacc[4] = {};
  const unsigned short* vhead = vT + ((size_t)head << 16) + (size_t)(c0 + li)*512;
  #pragma unroll
  for (int kt = 0; kt < 16; ++kt){
    const int kp0 = kt*32 + g*8;
    const s16x8 vb = *(const s16x8*)&vhead[kp0];
    #pragma unroll
    for (int mi = 0; mi < 4; ++mi){
      const s16x8 aw = *(const s16x8*)&wlds[swzi(mi*16 + li, kp0, 512)];
      yacc[mi] = MFMA_BF16(aw, vb, yacc[mi]);
    }
  }

  // epilogue: y = x + attn
  #pragma unroll
  for (int mi = 0; mi < 4; ++mi)
    #pragma unroll
    for (int r = 0; r < 4; ++r){
      const int row = mi*16 + g*4 + r;
      const size_t idx = (hbase + q0 + row)*128 + c0 + li;
      __builtin_nontemporal_store(x[idx] + yacc[mi][r], &y[idx]);
    }
}

extern "C" void kernel_launch(void* const* d_in, const int* in_sizes, int n_in,
                              void* d_out, int out_size, void* d_ws, size_t ws_size,
                              hipStream_t stream){
  (void)in_sizes; (void)n_in; (void)out_size; (void)ws_size;
  const float* x = (const float*)d_in[0];
  const float* W = (const float*)d_in[1];
  float* y    = (float*)d_out;                        // 33,554,432 f32
  float* wout = y + (size_t)33554432;                 // 134,217,728 f32

  char* ws = (char*)d_ws;
  unsigned short* qh  = (unsigned short*)(ws);                        // 32 MB
  unsigned short* ql  = (unsigned short*)(ws +  33554432ull);         // 32 MB
  unsigned short* kh  = (unsigned short*)(ws +  67108864ull);         // 32 MB
  unsigned short* kl  = (unsigned short*)(ws + 100663296ull);         // 32 MB
  unsigned short* vT  = (unsigned short*)(ws + 134217728ull);         // 64 MB
  unsigned short* wtH = (unsigned short*)(ws + 201326592ull);         // 64 KB
  unsigned short* wtL = (unsigned short*)(ws + 201392128ull);         // 64 KB

  hipLaunchKernelGGL(k0_wt,   dim3(256),  dim3(128), 0, stream, W, wtH, wtL);
  hipLaunchKernelGGL(k1_qkv,  dim3(2048), dim3(512), 0, stream, x, wtH, wtL,
                     qh, ql, kh, kl, vT);
  hipLaunchKernelGGL(k2_attn, dim3(4096), dim3(512), 0, stream,
                     qh, ql, kh, kl, vT, x, y, wout);
}

// Round 3
// 514.885 us; speedup vs baseline: 1.3034x; 1.3034x over previous
//
#include <hip/hip_runtime.h>
#include <hip/hip_bf16.h>

typedef short s16x8 __attribute__((ext_vector_type(8)));
typedef float f32x4 __attribute__((ext_vector_type(4)));

#define MFMA_BF16(a,b,c) __builtin_amdgcn_mfma_f32_16x16x32_bf16((a),(b),(c),0,0,0)

static __device__ __forceinline__ unsigned short f2bf(float f){
  unsigned u = __builtin_bit_cast(unsigned, f);
  u += 0x7fffu + ((u >> 16) & 1u);          // RNE
  return (unsigned short)(u >> 16);
}
static __device__ __forceinline__ float bf2f(unsigned short h){
  unsigned u = ((unsigned)h) << 16;
  return __builtin_bit_cast(float, u);
}
// XOR swizzle on 16B chunks; mask (row ^ row>>3)&7: write groups {r,4+r,8+r,12+r}
// land in >=2 distinct chunk slots (<=2-way = free), phase-E reads (16 consecutive
// rows, fixed chunk) spread 2-way. lw = row width in shorts.
static __device__ __forceinline__ int swzi(int row, int col, int lw){
  const int chunk = (col >> 3) ^ ((row ^ (row >> 3)) & 7);
  return row*lw + (chunk << 3) + (col & 7);
}

// ---------------- kernel 0: W transpose + hi/lo split ------------------------
__global__ __launch_bounds__(128) void k0_wt(const float* __restrict__ W,
                                             unsigned short* __restrict__ wtH,
                                             unsigned short* __restrict__ wtL){
  const int n = blockIdx.x;       // 0..255 output col
  const int c = threadIdx.x;      // 0..127 input ch
  const float v = W[(size_t)c*256 + n];
  const unsigned short h = f2bf(v);
  wtH[n*128 + c] = h;
  wtL[n*128 + c] = f2bf(v - bf2f(h));
}

// ---------------- kernel 1: qkv = x @ W (split-bf16) -------------------------
// q/k half computed operand-swapped (D[outch][pos]) -> per-lane 4 consecutive
// channels -> packed ushort4 stores into qh/ql/kh/kl [pos][64].
// v half computed normal (D[pos][ch]) -> per-lane 4 consecutive pos -> packed
// ushort4 stores into vT[head][ch][pos].
__global__ __launch_bounds__(512,2) void k1_qkv(const float* __restrict__ x,
    const unsigned short* __restrict__ wtH, const unsigned short* __restrict__ wtL,
    unsigned short* __restrict__ qh, unsigned short* __restrict__ ql,
    unsigned short* __restrict__ kh, unsigned short* __restrict__ kl,
    unsigned short* __restrict__ vT){
  __shared__ unsigned short xh[16384], xl[16384];   // 64 KB
  const int t = threadIdx.x;
  const int lane = t & 63, wid = t >> 6;
  const int li = lane & 15, g = lane >> 4;
  const int m0 = blockIdx.x * 128;
  const int wm = wid >> 2, wn = wid & 3;

  // stage x tile (128 rows x 128 ch), split hi/lo, swizzled
  {
    const int row = t >> 2, cb = (t & 3) * 32;
    const float* src = x + (size_t)(m0 + row)*128 + cb;
    #pragma unroll
    for (int gg = 0; gg < 4; ++gg){
      const float4 v0 = ((const float4*)src)[2*gg];
      const float4 v1 = ((const float4*)src)[2*gg + 1];
      const float vv[8] = {v0.x,v0.y,v0.z,v0.w,v1.x,v1.y,v1.z,v1.w};
      s16x8 h, l;
      #pragma unroll
      for (int j = 0; j < 8; ++j){
        const unsigned short hb = f2bf(vv[j]);
        h[j] = (short)hb;
        l[j] = (short)f2bf(vv[j] - bf2f(hb));
      }
      const int idx = swzi(row, cb + 8*gg, 128);
      *(s16x8*)&xh[idx] = h;
      *(s16x8*)&xl[idx] = l;
    }
  }
  __syncthreads();

  // ---- half 0: q,k (operand-swapped: D[m=outch][n=pos]) ----
  {
    f32x4 acc[4][2] = {};
    #pragma unroll
    for (int ks = 0; ks < 4; ++ks){
      const int col = ks*32 + g*8;
      s16x8 ah[4], al[4];
      #pragma unroll
      for (int mi = 0; mi < 4; ++mi){
        const int idx = swzi(wm*64 + mi*16 + li, col, 128);
        ah[mi] = *(const s16x8*)&xh[idx];
        al[mi] = *(const s16x8*)&xl[idx];
      }
      #pragma unroll
      for (int ni = 0; ni < 2; ++ni){
        const size_t boff = (size_t)(wn*32 + ni*16 + li)*128 + col;
        const s16x8 bh = *(const s16x8*)(wtH + boff);
        const s16x8 bl = *(const s16x8*)(wtL + boff);
        #pragma unroll
        for (int mi = 0; mi < 4; ++mi){
          acc[mi][ni] = MFMA_BF16(bh, ah[mi], acc[mi][ni]);   // A=W, B=x
          acc[mi][ni] = MFMA_BF16(bh, al[mi], acc[mi][ni]);
          acc[mi][ni] = MFMA_BF16(bl, ah[mi], acc[mi][ni]);
        }
      }
    }
    #pragma unroll
    for (int mi = 0; mi < 4; ++mi)
      #pragma unroll
      for (int ni = 0; ni < 2; ++ni){
        const int pos = m0 + wm*64 + mi*16 + li;
        const int och = wn*32 + ni*16 + g*4;
        ushort4 hv, lv;
        #pragma unroll
        for (int r = 0; r < 4; ++r){
          const float v = acc[mi][ni][r];
          const unsigned short hb = f2bf(v);
          ((unsigned short*)&hv)[r] = hb;
          ((unsigned short*)&lv)[r] = f2bf(v - bf2f(hb));
        }
        const size_t off = (size_t)pos*64 + (och & 63);
        if (wn < 2){ *(ushort4*)&qh[off] = hv; *(ushort4*)&ql[off] = lv; }
        else       { *(ushort4*)&kh[off] = hv; *(ushort4*)&kl[off] = lv; }
      }
  }

  // ---- half 1: v (normal: D[m=pos][n=ch]) ----
  {
    f32x4 acc[4][2] = {};
    #pragma unroll
    for (int ks = 0; ks < 4; ++ks){
      const int col = ks*32 + g*8;
      s16x8 ah[4], al[4];
      #pragma unroll
      for (int mi = 0; mi < 4; ++mi){
        const int idx = swzi(wm*64 + mi*16 + li, col, 128);
        ah[mi] = *(const s16x8*)&xh[idx];
        al[mi] = *(const s16x8*)&xl[idx];
      }
      #pragma unroll
      for (int ni = 0; ni < 2; ++ni){
        const size_t boff = (size_t)(128 + wn*32 + ni*16 + li)*128 + col;
        const s16x8 bh = *(const s16x8*)(wtH + boff);
        const s16x8 bl = *(const s16x8*)(wtL + boff);
        #pragma unroll
        for (int mi = 0; mi < 4; ++mi){
          acc[mi][ni] = MFMA_BF16(ah[mi], bh, acc[mi][ni]);
          acc[mi][ni] = MFMA_BF16(ah[mi], bl, acc[mi][ni]);
          acc[mi][ni] = MFMA_BF16(al[mi], bh, acc[mi][ni]);
        }
      }
    }
    #pragma unroll
    for (int mi = 0; mi < 4; ++mi)
      #pragma unroll
      for (int ni = 0; ni < 2; ++ni){
        const int growb = m0 + wm*64 + mi*16 + g*4;   // 4 consecutive pos
        const int ch = wn*32 + ni*16 + li;
        const int head = growb >> 9, posb = growb & 511;
        ushort4 pv;
        #pragma unroll
        for (int r = 0; r < 4; ++r)
          ((unsigned short*)&pv)[r] = f2bf(acc[mi][ni][r]);
        *(ushort4*)&vT[((size_t)head << 16) + ch*512 + posb] = pv;
      }
  }
}

// ---------------- kernel 2: scores -> softmax -> w out; y = x + w.v ---------
// 256 threads = 4 waves; block = 32 q rows; wave owns 128-k slice.
__global__ __launch_bounds__(256,4) void k2_attn(
    const unsigned short* __restrict__ qh, const unsigned short* __restrict__ ql,
    const unsigned short* __restrict__ kh, const unsigned short* __restrict__ kl,
    const unsigned short* __restrict__ vT, const float* __restrict__ x,
    float* __restrict__ y, float* __restrict__ wout){
  __shared__ unsigned short wlds[16384];          // 32 KB (swizzled bf16 w)
  __shared__ float redm[128], reds[128];          // 32 rows x 4 waves

  const int t = threadIdx.x;
  const int lane = t & 63, wid = t >> 6;
  const int li = lane & 15, g = lane >> 4;
  const int bi = blockIdx.x;
  // XCD-grouped: all 16 blocks of a head share an XCD (bi&7 = XCD)
  const int head = (bi & 7) + 8 * (bi >> 7);
  const int qt = (bi >> 3) & 15;
  const size_t hbase = (size_t)head * 512;
  const int q0 = qt * 32;
  const int kbase = wid * 128;                    // wave's k-slice

  // Phase B: scores(32 x 128-slice), fragments direct from global (L2-hot)
  f32x4 acc[2][8] = {};
  #pragma unroll
  for (int ks = 0; ks < 2; ++ks){
    const int col = ks*32 + g*8;
    s16x8 ah[2], al[2];
    #pragma unroll
    for (int mi = 0; mi < 2; ++mi){
      const size_t aoff = (hbase + q0 + mi*16 + li)*64 + col;
      ah[mi] = *(const s16x8*)(qh + aoff);
      al[mi] = *(const s16x8*)(ql + aoff);
    }
    #pragma unroll
    for (int ni = 0; ni < 8; ++ni){
      const size_t boff = (hbase + kbase + ni*16 + li)*64 + col;
      const s16x8 bh = *(const s16x8*)(kh + boff);
      const s16x8 bl = *(const s16x8*)(kl + boff);
      #pragma unroll
      for (int mi = 0; mi < 2; ++mi){
        acc[mi][ni] = MFMA_BF16(ah[mi], bh, acc[mi][ni]);
        acc[mi][ni] = MFMA_BF16(ah[mi], bl, acc[mi][ni]);
        acc[mi][ni] = MFMA_BF16(al[mi], bh, acc[mi][ni]);
      }
    }
  }

  // Phase C: softmax, ONE barrier. Per wave: slice max + slice expsum.
  #pragma unroll
  for (int mi = 0; mi < 2; ++mi)
    #pragma unroll
    for (int r = 0; r < 4; ++r){
      float m = acc[mi][0][r];
      #pragma unroll
      for (int ni = 1; ni < 8; ++ni) m = fmaxf(m, acc[mi][ni][r]);
      #pragma unroll
      for (int d = 1; d < 16; d <<= 1) m = fmaxf(m, __shfl_xor(m, d));
      float s = 0.f;
      #pragma unroll
      for (int ni = 0; ni < 8; ++ni) s += __expf(acc[mi][ni][r] - m);
      #pragma unroll
      for (int d = 1; d < 16; d <<= 1) s += __shfl_xor(s, d);
      if (li == 0){
        const int row = mi*16 + g*4 + r;
        redm[row*4 + wid] = m;
        reds[row*4 + wid] = s;
      }
    }
  __syncthreads();

  float Mrow[2][4], Irow[2][4];
  #pragma unroll
  for (int mi = 0; mi < 2; ++mi)
    #pragma unroll
    for (int r = 0; r < 4; ++r){
      const int row = mi*16 + g*4 + r;
      const float4 mv = *(const float4*)&redm[row*4];
      const float4 sv = *(const float4*)&reds[row*4];
      const float M = fmaxf(fmaxf(mv.x, mv.y), fmaxf(mv.z, mv.w));
      const float S = sv.x*__expf(mv.x - M) + sv.y*__expf(mv.y - M)
                    + sv.z*__expf(mv.z - M) + sv.w*__expf(mv.w - M);
      Mrow[mi][r] = M;
      Irow[mi][r] = 1.0f / S;
    }

  // Phase D: w = exp(s-M)/S; write wout (NT) + stash bf16 in LDS
  #pragma unroll
  for (int mi = 0; mi < 2; ++mi)
    #pragma unroll
    for (int ni = 0; ni < 8; ++ni)
      #pragma unroll
      for (int r = 0; r < 4; ++r){
        const int row = mi*16 + g*4 + r;
        const int col = kbase + ni*16 + li;
        const float wv = __expf(acc[mi][ni][r] - Mrow[mi][r]) * Irow[mi][r];
        __builtin_nontemporal_store(wv, &wout[(hbase + q0 + row)*512 + col]);
        wlds[swzi(row, col, 512)] = f2bf(wv);
      }
  __syncthreads();

  // Phase E: y-tile = w . v ; wave owns 32 output channels
  const int c0 = wid * 32;
  f32x4 yacc[2][2] = {};
  #pragma unroll
  for (int kt = 0; kt < 16; ++kt){
    const int kp0 = kt*32 + g*8;
    s16x8 aw[2], vb[2];
    #pragma unroll
    for (int mi = 0; mi < 2; ++mi)
      aw[mi] = *(const s16x8*)&wlds[swzi(mi*16 + li, kp0, 512)];
    #pragma unroll
    for (int ci = 0; ci < 2; ++ci)
      vb[ci] = *(const s16x8*)&vT[((size_t)head << 16) + (size_t)(c0 + ci*16 + li)*512 + kp0];
    #pragma unroll
    for (int mi = 0; mi < 2; ++mi)
      #pragma unroll
      for (int ci = 0; ci < 2; ++ci)
        yacc[mi][ci] = MFMA_BF16(aw[mi], vb[ci], yacc[mi][ci]);
  }

  // epilogue: y = x + attn
  #pragma unroll
  for (int mi = 0; mi < 2; ++mi)
    #pragma unroll
    for (int ci = 0; ci < 2; ++ci)
      #pragma unroll
      for (int r = 0; r < 4; ++r){
        const int row = mi*16 + g*4 + r;
        const size_t idx = (hbase + q0 + row)*128 + c0 + ci*16 + li;
        const float xv = __builtin_nontemporal_load(&x[idx]);
        __builtin_nontemporal_store(xv + yacc[mi][ci][r], &y[idx]);
      }
}

extern "C" void kernel_launch(void* const* d_in, const int* in_sizes, int n_in,
                              void* d_out, int out_size, void* d_ws, size_t ws_size,
                              hipStream_t stream){
  (void)in_sizes; (void)n_in; (void)out_size; (void)ws_size;
  const float* x = (const float*)d_in[0];
  const float* W = (const float*)d_in[1];
  float* y    = (float*)d_out;                        // 33,554,432 f32
  float* wout = y + (size_t)33554432;                 // 134,217,728 f32

  char* ws = (char*)d_ws;
  unsigned short* qh  = (unsigned short*)(ws);                        // 32 MB
  unsigned short* ql  = (unsigned short*)(ws +  33554432ull);         // 32 MB
  unsigned short* kh  = (unsigned short*)(ws +  67108864ull);         // 32 MB
  unsigned short* kl  = (unsigned short*)(ws + 100663296ull);         // 32 MB
  unsigned short* vT  = (unsigned short*)(ws + 134217728ull);         // 64 MB
  unsigned short* wtH = (unsigned short*)(ws + 201326592ull);         // 64 KB
  unsigned short* wtL = (unsigned short*)(ws + 201392128ull);         // 64 KB

  hipLaunchKernelGGL(k0_wt,   dim3(256),  dim3(128), 0, stream, W, wtH, wtL);
  hipLaunchKernelGGL(k1_qkv,  dim3(2048), dim3(512), 0, stream, x, wtH, wtL,
                     qh, ql, kh, kl, vT);
  hipLaunchKernelGGL(k2_attn, dim3(8192), dim3(256), 0, stream,
                     qh, ql, kh, kl, vT, x, y, wout);
}